// Round 1
// baseline (1722.909 us; speedup 1.0000x reference)
//
#include <hip/hip_runtime.h>
#include <math.h>

#define T_DIM 4096
#define D_DIM 256
#define K_NUM 1024
#define B_NUM 16
#define N_TOT (B_NUM * T_DIM)   // 65536
#define PADD 260                 // column-major LDS pad: 260*4B rows, float4-aligned

// ---------------- ws layout ----------------
// [0,4)              float loss_sum
// [4, 4+4096)        int   hist[1024]
// [8192, +262144)    int   qidx[65536]
// [270336, +4096)    float e2[1024]
// total ~268 KB

// ---------------- kernel A: |e_k|^2 ----------------
__global__ __launch_bounds__(256) void e2_kernel(const float* __restrict__ embed,
                                                 float* __restrict__ e2) {
    const int wave = threadIdx.x >> 6;
    const int lane = threadIdx.x & 63;
    const int k = blockIdx.x * 4 + wave;          // 256 blocks * 4 waves = 1024 k
    const float4* row = (const float4*)(embed + (size_t)k * D_DIM);
    float4 v = row[lane];                         // 64 float4 = 256 floats, coalesced
    float s = v.x * v.x + v.y * v.y + v.z * v.z + v.w * v.w;
    #pragma unroll
    for (int off = 32; off; off >>= 1) s += __shfl_down(s, off);
    if (lane == 0) e2[k] = s;
}

// ---------------- kernel B: fused distance GEMM + argmin ----------------
// grid (T/64, B), block 256. Workgroup: 64 columns x all 1024 codewords.
// Wave w handles k in [w*256, w*256+256), thread = 1 column, 8 k accumulators.
__global__ __launch_bounds__(256, 2) void argmin_kernel(
    const float* __restrict__ x, const float* __restrict__ embed,
    const float* __restrict__ e2, int* __restrict__ qidx)
{
    __shared__ float xs[64 * PADD];   // xs[t][d], col-major tile, 66560 B
    __shared__ float rv[4][64];
    __shared__ int   ri[4][64];

    const int tid  = threadIdx.x;
    const int lane = tid & 63;
    const int t0   = blockIdx.x * 64;
    const int b    = blockIdx.y;
    const float* xb = x + (size_t)b * D_DIM * T_DIM;

    // stage x tile: xs[t][d] = x[b][d][t0+t]; each wave loads one row of 64 consecutive t
    #pragma unroll 8
    for (int i = 0; i < 64; ++i) {
        const int d = i * 4 + (tid >> 6);
        xs[lane * PADD + d] = xb[(size_t)d * T_DIM + t0 + lane];
    }
    __syncthreads();

    const int wave = __builtin_amdgcn_readfirstlane(tid >> 6);  // SGPR -> scalar E loads
    float bestv = 3.4e38f;
    int   besti = 0;

    const float* xrow = xs + lane * PADD;
    for (int kc = 0; kc < 32; ++kc) {
        const int kbase = wave * 256 + kc * 8;
        float acc[8];
        #pragma unroll
        for (int j = 0; j < 8; ++j) acc[j] = 0.f;

        #pragma unroll 8
        for (int dc = 0; dc < 32; ++dc) {
            const float4 xa = *(const float4*)(xrow + dc * 8);
            const float4 xc = *(const float4*)(xrow + dc * 8 + 4);
            #pragma unroll
            for (int j = 0; j < 8; ++j) {
                const float* er = embed + (size_t)(kbase + j) * D_DIM + dc * 8;
                const float4 ea = *(const float4*)(er);
                const float4 eb = *(const float4*)(er + 4);
                acc[j] += ea.x * xa.x + ea.y * xa.y + ea.z * xa.z + ea.w * xa.w
                        + eb.x * xc.x + eb.y * xc.y + eb.z * xc.z + eb.w * xc.w;
            }
        }
        #pragma unroll
        for (int j = 0; j < 8; ++j) {
            const float s = e2[kbase + j] - 2.f * acc[j];
            if (s < bestv) { bestv = s; besti = kbase + j; }   // strict <: lowest k wins ties
        }
    }

    rv[wave][lane] = bestv;
    ri[wave][lane] = besti;
    __syncthreads();
    if (tid < 64) {
        float bv = rv[0][tid];
        int   bi = ri[0][tid];
        #pragma unroll
        for (int w = 1; w < 4; ++w) {
            const float v = rv[w][tid];
            const int   iw = ri[w][tid];
            if (v < bv) { bv = v; bi = iw; }  // ascending wave = ascending k: ties keep low k
        }
        qidx[b * T_DIM + t0 + tid] = bi;
    }
}

// ---------------- kernel C: gather z_q + loss partial + histogram ----------------
__global__ __launch_bounds__(256) void gather_kernel(
    const float* __restrict__ x, const float* __restrict__ embed,
    const int* __restrict__ qidx, float* __restrict__ out,
    float* __restrict__ loss_sum, int* __restrict__ hist)
{
    const int tid = threadIdx.x;
    const int n = blockIdx.x * 256 + tid;
    const int b = n >> 12;          // /4096
    const int t = n & 4095;
    const int idx = qidx[n];
    atomicAdd(&hist[idx], 1);

    const float* xp = x + (size_t)b * D_DIM * T_DIM + t;
    float*       op = out + (size_t)b * D_DIM * T_DIM + t;
    const float4* ep = (const float4*)(embed + (size_t)idx * D_DIM);

    float local = 0.f;
    #pragma unroll 4
    for (int dc = 0; dc < 64; ++dc) {
        const float4 ev = ep[dc];           // gather, L1/L2-resident (1 MB codebook)
        const size_t d = (size_t)dc * 4;
        const float xv0 = xp[(d + 0) * T_DIM];
        const float xv1 = xp[(d + 1) * T_DIM];
        const float xv2 = xp[(d + 2) * T_DIM];
        const float xv3 = xp[(d + 3) * T_DIM];
        op[(d + 0) * T_DIM] = ev.x;
        op[(d + 1) * T_DIM] = ev.y;
        op[(d + 2) * T_DIM] = ev.z;
        op[(d + 3) * T_DIM] = ev.w;
        float d0 = ev.x - xv0, d1 = ev.y - xv1, d2 = ev.z - xv2, d3 = ev.w - xv3;
        local = fmaf(d0, d0, local);
        local = fmaf(d1, d1, local);
        local = fmaf(d2, d2, local);
        local = fmaf(d3, d3, local);
    }

    #pragma unroll
    for (int off = 32; off; off >>= 1) local += __shfl_down(local, off);
    __shared__ float ls[4];
    if ((tid & 63) == 0) ls[tid >> 6] = local;
    __syncthreads();
    if (tid == 0) atomicAdd(loss_sum, ls[0] + ls[1] + ls[2] + ls[3]);
}

// ---------------- kernel D: entropy / finalize ----------------
__global__ __launch_bounds__(256) void finalize_kernel(
    const int* __restrict__ hist, const float* __restrict__ loss_sum,
    float* __restrict__ out)
{
    const int tid = threadIdx.x;
    float acc = 0.f;
    #pragma unroll
    for (int i = tid; i < K_NUM; i += 256) {
        const float p = (float)hist[i] * (1.f / (float)N_TOT);
        acc += p * logf(p + 1e-10f);
    }
    #pragma unroll
    for (int off = 32; off; off >>= 1) acc += __shfl_down(acc, off);
    __shared__ float ls[4];
    if ((tid & 63) == 0) ls[tid >> 6] = acc;
    __syncthreads();
    if (tid == 0) {
        const float H = -(ls[0] + ls[1] + ls[2] + ls[3]);
        const size_t base = (size_t)N_TOT * D_DIM;   // 16777216
        out[base] = 1.25f * loss_sum[0] * (1.f / 16777216.f);
        const float kld = (float)(6.931471805599453 * 4096.0);  // log(1024)*T
        #pragma unroll
        for (int i = 0; i < 16; ++i) out[base + 1 + i] = kld;
        out[base + 17] = expf(H);
    }
}

extern "C" void kernel_launch(void* const* d_in, const int* in_sizes, int n_in,
                              void* d_out, int out_size, void* d_ws, size_t ws_size,
                              hipStream_t stream)
{
    const float* x     = (const float*)d_in[0];   // (16, 256, 4096) f32
    const float* embed = (const float*)d_in[1];   // (1024, 256) f32
    float* out = (float*)d_out;

    char* ws = (char*)d_ws;
    float* loss_sum = (float*)(ws);
    int*   hist     = (int*)(ws + 4);
    int*   qidx     = (int*)(ws + 8192);
    float* e2       = (float*)(ws + 8192 + 262144);

    hipMemsetAsync(ws, 0, 8192, stream);  // zero loss_sum + hist
    e2_kernel<<<256, 256, 0, stream>>>(embed, e2);
    argmin_kernel<<<dim3(T_DIM / 64, B_NUM), 256, 0, stream>>>(x, embed, e2, qidx);
    gather_kernel<<<N_TOT / 256, 256, 0, stream>>>(x, embed, qidx, out, loss_sum, hist);
    finalize_kernel<<<1, 256, 0, stream>>>(hist, loss_sum, out);
}

// Round 2
// 346.568 us; speedup vs baseline: 4.9713x; 4.9713x over previous
//
#include <hip/hip_runtime.h>
#include <math.h>

#define T_DIM 4096
#define D_DIM 256
#define K_NUM 1024
#define B_NUM 16
#define N_TOT (B_NUM * T_DIM)   // 65536
#define EPS_FLAG 0.03f

typedef short short8 __attribute__((ext_vector_type(8)));
typedef float f32x4 __attribute__((ext_vector_type(4)));

// ---------------- ws layout (bytes) ----------------
// 0        flagcnt (int)
// 4        loss_sum (float)
// 64       hist[1024] (4 KB)
// 4352     e2[1024] (4 KB)
// 8704     qidx[65536] (256 KB)
// 270848   flaglist[65536] (256 KB)
// 540672   eswz (1 MB)  -- bf16 hi/lo split of embed, fragment-swizzled
#define WS_FLAGCNT 0
#define WS_LOSS 4
#define WS_HIST 64
#define WS_E2 4352
#define WS_QIDX 8704
#define WS_FLAGLIST 270848
#define WS_ESWZ 540672

__device__ inline unsigned short bf16r(float v) {
    unsigned u = __float_as_uint(v);
    unsigned r = u + 0x7FFFu + ((u >> 16) & 1u);
    return (unsigned short)(r >> 16);
}

// ---------------- kernel: |e_k|^2 (exact fp32) ----------------
__global__ __launch_bounds__(256) void e2_kernel(const float* __restrict__ embed,
                                                 float* __restrict__ e2) {
    const int wave = threadIdx.x >> 6;
    const int lane = threadIdx.x & 63;
    const int k = blockIdx.x * 4 + wave;
    const float4* row = (const float4*)(embed + (size_t)k * D_DIM);
    float4 v = row[lane];
    float s = v.x * v.x + v.y * v.y + v.z * v.z + v.w * v.w;
    #pragma unroll
    for (int off = 32; off; off >>= 1) s += __shfl_down(s, off);
    if (lane == 0) e2[k] = s;
}

// ---------------- kernel: split embed into bf16 hi/lo, fragment-swizzled ----------------
// chunk g (16 cols), layout per chunk (16384 B): [kstep 0..7: hi 1KB][hi...][+8192: lo]
// within a 1KB kstep block: lane l -> 16 B = 8 bf16 for col=g*16+(l&15), d=k*32+(l>>4)*8+j
__global__ __launch_bounds__(256) void prep_eswz_kernel(const float* __restrict__ embed,
                                                        unsigned char* __restrict__ eswz) {
    const int tau = blockIdx.x * 256 + threadIdx.x;   // 0..32767
    const int g = tau >> 9;
    const int k = (tau >> 6) & 7;
    const int l = tau & 63;
    const int col = g * 16 + (l & 15);
    const int d0 = k * 32 + ((l >> 4) << 3);
    const float* src = embed + (size_t)col * D_DIM + d0;
    short8 hi, lo;
    #pragma unroll
    for (int j = 0; j < 8; ++j) {
        float v = src[j];
        unsigned short hs = bf16r(v);
        float hif = __uint_as_float((unsigned)hs << 16);
        unsigned short ls = bf16r(v - hif);
        hi[j] = (short)hs; lo[j] = (short)ls;
    }
    *(short8*)(eswz + (size_t)g * 16384 + k * 1024 + l * 16) = hi;
    *(short8*)(eswz + (size_t)g * 16384 + 8192 + k * 1024 + l * 16) = lo;
}

// ---------------- kernel: MFMA distance + top-2 argmin ----------------
// grid 512 blocks x 256 threads. Block owns 128 rows; wave owns 32 (2 A row-frags).
// Loops 64 col-chunks of 16; B chunk staged in LDS (single 16KB buffer, reg prefetch).
__global__ __launch_bounds__(256, 2) void argmin_mfma_kernel(
    const float* __restrict__ x, const unsigned char* __restrict__ eswz,
    const float* __restrict__ e2, int* __restrict__ qidx,
    int* __restrict__ flagcnt, int* __restrict__ flaglist)
{
    __shared__ __align__(16) unsigned char bbuf[16384];
    __shared__ float e2s[K_NUM];

    const int tid = threadIdx.x;
    const int w = tid >> 6;
    const int l = tid & 63;
    const int rb = blockIdx.x * 128;
    const int b = rb >> 12;
    const float* xb = x + (size_t)b * (D_DIM * T_DIM);

    for (int i = tid; i < K_NUM; i += 256) e2s[i] = e2[i];

    // prefetch regs for chunk 0
    float4 pf0, pf1, pf2, pf3;
    {
        const float4* src = (const float4*)(eswz + (size_t)tid * 16);
        pf0 = src[0]; pf1 = src[256]; pf2 = src[512]; pf3 = src[768];
    }

    // ---- load + convert A fragments (resident): 2 row-frags x 8 ksteps ----
    short8 Ah[2][8], Al[2][8];
    #pragma unroll
    for (int f = 0; f < 2; ++f) {
        const int row = rb + w * 32 + f * 16 + (l & 15);
        const int t = row & (T_DIM - 1);
        const float* xp = xb + t;
        #pragma unroll
        for (int k = 0; k < 8; ++k) {
            const int d0 = k * 32 + ((l >> 4) << 3);
            short8 hi, lo;
            #pragma unroll
            for (int j = 0; j < 8; ++j) {
                float v = xp[(size_t)(d0 + j) * T_DIM];
                unsigned short hs = bf16r(v);
                float hif = __uint_as_float((unsigned)hs << 16);
                unsigned short ls = bf16r(v - hif);
                hi[j] = (short)hs; lo[j] = (short)ls;
            }
            Ah[f][k] = hi; Al[f][k] = lo;
        }
    }

    float bestv[8], secv[8];
    int   besti[8];
    #pragma unroll
    for (int s = 0; s < 8; ++s) { bestv[s] = 3.4e38f; secv[s] = 3.4e38f; besti[s] = 0x7FFFFFFF; }

    for (int g = 0; g < 64; ++g) {
        __syncthreads();                         // previous chunk's compute done
        {   // write prefetched B chunk to LDS
            float4* dst = (float4*)(bbuf + tid * 16);
            dst[0] = pf0; dst[256] = pf1; dst[512] = pf2; dst[768] = pf3;
        }
        __syncthreads();                         // B chunk visible
        if (g + 1 < 64) {                        // issue next chunk's loads (overlap compute)
            const float4* src = (const float4*)(eswz + (size_t)(g + 1) * 16384 + (size_t)tid * 16);
            pf0 = src[0]; pf1 = src[256]; pf2 = src[512]; pf3 = src[768];
        }

        f32x4 acc0 = {0.f, 0.f, 0.f, 0.f};
        f32x4 acc1 = {0.f, 0.f, 0.f, 0.f};
        #pragma unroll
        for (int k = 0; k < 8; ++k) {
            short8 bh = *(const short8*)(bbuf + k * 1024 + l * 16);
            short8 bl = *(const short8*)(bbuf + 8192 + k * 1024 + l * 16);
            acc0 = __builtin_amdgcn_mfma_f32_16x16x32_bf16(Ah[0][k], bh, acc0, 0, 0, 0);
            acc0 = __builtin_amdgcn_mfma_f32_16x16x32_bf16(Ah[0][k], bl, acc0, 0, 0, 0);
            acc0 = __builtin_amdgcn_mfma_f32_16x16x32_bf16(Al[0][k], bh, acc0, 0, 0, 0);
            acc1 = __builtin_amdgcn_mfma_f32_16x16x32_bf16(Ah[1][k], bh, acc1, 0, 0, 0);
            acc1 = __builtin_amdgcn_mfma_f32_16x16x32_bf16(Ah[1][k], bl, acc1, 0, 0, 0);
            acc1 = __builtin_amdgcn_mfma_f32_16x16x32_bf16(Al[1][k], bh, acc1, 0, 0, 0);
        }

        const int col = g * 16 + (l & 15);
        const float e2c = e2s[col];
        #pragma unroll
        for (int r = 0; r < 4; ++r) {
            float s0 = e2c - 2.f * acc0[r];
            if (s0 < bestv[r]) { secv[r] = bestv[r]; bestv[r] = s0; besti[r] = col; }
            else if (s0 < secv[r]) secv[r] = s0;
            float s1 = e2c - 2.f * acc1[r];
            if (s1 < bestv[4 + r]) { secv[4 + r] = bestv[4 + r]; bestv[4 + r] = s1; besti[4 + r] = col; }
            else if (s1 < secv[4 + r]) secv[4 + r] = s1;
        }
    }

    // merge top-2 across the 16 lanes that share each row (xor 1,2,4,8 stays in-group)
    #pragma unroll
    for (int slot = 0; slot < 8; ++slot) {
        float bv = bestv[slot], sv = secv[slot];
        int bi = besti[slot];
        #pragma unroll
        for (int d = 1; d < 16; d <<= 1) {
            float ob = __shfl_xor(bv, d);
            int   oi = __shfl_xor(bi, d);
            float os = __shfl_xor(sv, d);
            bool take = (ob < bv) || (ob == bv && oi < bi);
            float loser = take ? bv : ob;
            bv = take ? ob : bv;
            bi = take ? oi : bi;
            sv = fminf(fminf(sv, os), loser);
        }
        if ((l & 15) == 0) {
            const int row = rb + w * 32 + (slot >> 2) * 16 + (l >> 4) * 4 + (slot & 3);
            qidx[row] = bi;
            if (sv - bv < EPS_FLAG) {
                int p = atomicAdd(flagcnt, 1);
                flaglist[p] = row;
            }
        }
    }
}

// ---------------- kernel: exact fp32 re-resolve for flagged (near-tie) rows ----------------
__global__ __launch_bounds__(256) void cleanup_kernel(
    const float* __restrict__ x, const float* __restrict__ embed,
    const float* __restrict__ e2, const int* __restrict__ flagcnt,
    const int* __restrict__ flaglist, int* __restrict__ qidx)
{
    __shared__ float xr[256];
    __shared__ float rv[256];
    __shared__ int   rix[256];
    const int tid = threadIdx.x;
    int cnt = flagcnt[0];
    if (cnt > N_TOT) cnt = N_TOT;
    for (int it = blockIdx.x; it < cnt; it += gridDim.x) {
        const int row = flaglist[it];
        const int b = row >> 12, t = row & (T_DIM - 1);
        __syncthreads();
        xr[tid] = x[(size_t)b * (D_DIM * T_DIM) + (size_t)tid * T_DIM + t];
        __syncthreads();
        float best = 3.4e38f; int bi = 0x7FFFFFFF;
        for (int q = 0; q < 4; ++q) {
            const int c = q * 256 + tid;
            const float4* ep = (const float4*)(embed + (size_t)c * D_DIM);
            float acc = 0.f;
            #pragma unroll 8
            for (int dd = 0; dd < 64; ++dd) {
                float4 ev = ep[dd];
                acc = fmaf(ev.x, xr[dd * 4 + 0], acc);
                acc = fmaf(ev.y, xr[dd * 4 + 1], acc);
                acc = fmaf(ev.z, xr[dd * 4 + 2], acc);
                acc = fmaf(ev.w, xr[dd * 4 + 3], acc);
            }
            const float s = e2[c] - 2.f * acc;
            if (s < best || (s == best && c < bi)) { best = s; bi = c; }
        }
        rv[tid] = best; rix[tid] = bi;
        __syncthreads();
        for (int off = 128; off; off >>= 1) {
            if (tid < off) {
                float ov = rv[tid + off]; int oi = rix[tid + off];
                if (ov < rv[tid] || (ov == rv[tid] && oi < rix[tid])) { rv[tid] = ov; rix[tid] = oi; }
            }
            __syncthreads();
        }
        if (tid == 0) qidx[row] = rix[0];
    }
}

// ---------------- kernel: gather z_q (LDS transpose) + loss + histogram ----------------
__global__ __launch_bounds__(256) void gather_kernel(
    const float* __restrict__ x, const float* __restrict__ embed,
    const int* __restrict__ qidx, float* __restrict__ out,
    float* __restrict__ loss_sum, int* __restrict__ hist)
{
    __shared__ float es[256 * 65];   // es[d][t], pad 65 -> conflict-free
    __shared__ int idxs[64];
    __shared__ float ls[4];
    const int tid = threadIdx.x;
    const int b = blockIdx.y, t0 = blockIdx.x * 64;
    if (tid < 64) {
        int i = qidx[b * T_DIM + t0 + tid];
        idxs[tid] = i;
        atomicAdd(&hist[i], 1);
    }
    __syncthreads();
    // phase 1: thread == d; coalesced embed row reads -> transposed LDS
    #pragma unroll 8
    for (int r = 0; r < 64; ++r)
        es[tid * 65 + r] = embed[(size_t)idxs[r] * D_DIM + tid];
    __syncthreads();
    // phase 2: coalesced t-major writes + fused loss
    const int t = tid & 63, dq = tid >> 6;
    const float* xp = x + (size_t)b * (D_DIM * T_DIM) + t0 + t;
    float*       op = out + (size_t)b * (D_DIM * T_DIM) + t0 + t;
    float local = 0.f;
    #pragma unroll 8
    for (int i = 0; i < 64; ++i) {
        const int d = dq * 64 + i;
        float e = es[d * 65 + t];
        float xv = xp[(size_t)d * T_DIM];
        op[(size_t)d * T_DIM] = e;
        float df = e - xv;
        local = fmaf(df, df, local);
    }
    #pragma unroll
    for (int off = 32; off; off >>= 1) local += __shfl_down(local, off);
    if ((tid & 63) == 0) ls[tid >> 6] = local;
    __syncthreads();
    if (tid == 0) atomicAdd(loss_sum, ls[0] + ls[1] + ls[2] + ls[3]);
}

// ---------------- kernel: entropy / finalize ----------------
__global__ __launch_bounds__(256) void finalize_kernel(
    const int* __restrict__ hist, const float* __restrict__ loss_sum,
    float* __restrict__ out)
{
    const int tid = threadIdx.x;
    float acc = 0.f;
    #pragma unroll
    for (int i = tid; i < K_NUM; i += 256) {
        const float p = (float)hist[i] * (1.f / (float)N_TOT);
        acc += p * logf(p + 1e-10f);
    }
    #pragma unroll
    for (int off = 32; off; off >>= 1) acc += __shfl_down(acc, off);
    __shared__ float ls[4];
    if ((tid & 63) == 0) ls[tid >> 6] = acc;
    __syncthreads();
    if (tid == 0) {
        const float H = -(ls[0] + ls[1] + ls[2] + ls[3]);
        const size_t base = (size_t)N_TOT * D_DIM;   // 16777216
        out[base] = 1.25f * loss_sum[0] * (1.f / 16777216.f);
        const float kld = (float)(6.931471805599453 * 4096.0);  // log(1024)*T
        #pragma unroll
        for (int i = 0; i < 16; ++i) out[base + 1 + i] = kld;
        out[base + 17] = expf(H);
    }
}

extern "C" void kernel_launch(void* const* d_in, const int* in_sizes, int n_in,
                              void* d_out, int out_size, void* d_ws, size_t ws_size,
                              hipStream_t stream)
{
    const float* x     = (const float*)d_in[0];   // (16, 256, 4096) f32
    const float* embed = (const float*)d_in[1];   // (1024, 256) f32
    float* out = (float*)d_out;

    char* ws = (char*)d_ws;
    int*   flagcnt  = (int*)(ws + WS_FLAGCNT);
    float* loss_sum = (float*)(ws + WS_LOSS);
    int*   hist     = (int*)(ws + WS_HIST);
    float* e2       = (float*)(ws + WS_E2);
    int*   qidx     = (int*)(ws + WS_QIDX);
    int*   flaglist = (int*)(ws + WS_FLAGLIST);
    unsigned char* eswz = (unsigned char*)(ws + WS_ESWZ);

    hipMemsetAsync(ws, 0, 4160, stream);  // flagcnt + loss_sum + hist

    e2_kernel<<<K_NUM / 4, 256, 0, stream>>>(embed, e2);
    prep_eswz_kernel<<<128, 256, 0, stream>>>(embed, eswz);
    argmin_mfma_kernel<<<N_TOT / 128, 256, 0, stream>>>(x, eswz, e2, qidx, flagcnt, flaglist);
    cleanup_kernel<<<128, 256, 0, stream>>>(x, embed, e2, flagcnt, flaglist, qidx);
    gather_kernel<<<dim3(T_DIM / 64, B_NUM), 256, 0, stream>>>(x, embed, qidx, out, loss_sum, hist);
    finalize_kernel<<<1, 256, 0, stream>>>(hist, loss_sum, out);
}

// Round 3
// 297.633 us; speedup vs baseline: 5.7887x; 1.1644x over previous
//
#include <hip/hip_runtime.h>
#include <math.h>

#define T_DIM 4096
#define D_DIM 256
#define K_NUM 1024
#define B_NUM 16
#define N_TOT (B_NUM * T_DIM)   // 65536
#define EPS_FLAG 0.03f

typedef short short8 __attribute__((ext_vector_type(8)));
typedef float f32x4 __attribute__((ext_vector_type(4)));

// ---------------- ws layout (bytes) ----------------
#define WS_FLAGCNT 0
#define WS_LOSS 4
#define WS_HIST 64
#define WS_E2 4352
#define WS_QIDX 8704
#define WS_FLAGLIST 270848
#define WS_ESWZ 540672          // 1 MB: bf16 hi/lo split of embed, fragment-swizzled

__device__ inline unsigned short bf16r(float v) {
    unsigned u = __float_as_uint(v);
    unsigned r = u + 0x7FFFu + ((u >> 16) & 1u);
    return (unsigned short)(r >> 16);
}

// async 16B global->LDS (no VGPR roundtrip). LDS dest is wave-uniform base + lane*16.
__device__ inline void gl_lds16(const void* g, void* l) {
    __builtin_amdgcn_global_load_lds(
        (const __attribute__((address_space(1))) unsigned int*)g,
        (__attribute__((address_space(3))) unsigned int*)l, 16, 0, 0);
}

// ---------------- kernel: |e_k|^2 (exact fp32) ----------------
__global__ __launch_bounds__(256) void e2_kernel(const float* __restrict__ embed,
                                                 float* __restrict__ e2) {
    const int wave = threadIdx.x >> 6;
    const int lane = threadIdx.x & 63;
    const int k = blockIdx.x * 4 + wave;
    const float4* row = (const float4*)(embed + (size_t)k * D_DIM);
    float4 v = row[lane];
    float s = v.x * v.x + v.y * v.y + v.z * v.z + v.w * v.w;
    #pragma unroll
    for (int off = 32; off; off >>= 1) s += __shfl_down(s, off);
    if (lane == 0) e2[k] = s;
}

// ---------------- kernel: split embed into bf16 hi/lo, fragment-swizzled ----------------
// 16-col group g (16384 B): [k 0..7: hi 1KB each][+8192: lo]. lane l -> 16 B:
// col=g*16+(l&15), d=k*32+(l>>4)*8+j  (verified m89/m91 B-fragment layout)
__global__ __launch_bounds__(256) void prep_eswz_kernel(const float* __restrict__ embed,
                                                        unsigned char* __restrict__ eswz) {
    const int tau = blockIdx.x * 256 + threadIdx.x;   // 0..32767
    const int g = tau >> 9;
    const int k = (tau >> 6) & 7;
    const int l = tau & 63;
    const int col = g * 16 + (l & 15);
    const int d0 = k * 32 + ((l >> 4) << 3);
    const float* src = embed + (size_t)col * D_DIM + d0;
    short8 hi, lo;
    #pragma unroll
    for (int j = 0; j < 8; ++j) {
        float v = src[j];
        unsigned short hs = bf16r(v);
        float hif = __uint_as_float((unsigned)hs << 16);
        unsigned short ls = bf16r(v - hif);
        hi[j] = (short)hs; lo[j] = (short)ls;
    }
    *(short8*)(eswz + (size_t)g * 16384 + k * 1024 + l * 16) = hi;
    *(short8*)(eswz + (size_t)g * 16384 + 8192 + k * 1024 + l * 16) = lo;
}

// ---------------- kernel: MFMA distance + top-2 argmin ----------------
// 512 blocks x 256 thr. Block: 128 rows x all 1024 cols; wave: 32 rows (2 frags).
// 32 chunks of 32 cols; async global_load_lds double-buffer; 1 barrier/chunk;
// 4 independent accumulator chains per wave.
__global__ __launch_bounds__(256, 2) void argmin_mfma_kernel(
    const float* __restrict__ x, const unsigned char* __restrict__ eswz,
    const float* __restrict__ e2, int* __restrict__ qidx,
    int* __restrict__ flagcnt, int* __restrict__ flaglist)
{
    __shared__ __align__(16) unsigned char bbuf[2][32768];
    __shared__ float e2s[K_NUM];

    const int tid = threadIdx.x;
    const int w = tid >> 6;
    const int l = tid & 63;
    const int rb = blockIdx.x * 128;
    const int b = rb >> 12;
    const float* xb = x + (size_t)b * (D_DIM * T_DIM);

    // issue chunk 0 (overlaps A conversion below)
    {
        const unsigned char* src = eswz + (size_t)tid * 16;
        #pragma unroll
        for (int r = 0; r < 8; ++r) gl_lds16(src + r * 4096, &bbuf[0][tid * 16 + r * 4096]);
    }
    for (int i = tid; i < K_NUM; i += 256) e2s[i] = e2[i];

    // ---- load + convert A fragments (resident): 2 row-frags x 8 ksteps, hi/lo ----
    short8 Ah[2][8], Al[2][8];
    #pragma unroll
    for (int f = 0; f < 2; ++f) {
        const int row = rb + w * 32 + f * 16 + (l & 15);
        const int t = row & (T_DIM - 1);
        const float* xp = xb + t;
        #pragma unroll
        for (int k = 0; k < 8; ++k) {
            const int d0 = k * 32 + ((l >> 4) << 3);
            short8 hi, lo;
            #pragma unroll
            for (int j = 0; j < 8; ++j) {
                float v = xp[(size_t)(d0 + j) * T_DIM];
                unsigned short hs = bf16r(v);
                float hif = __uint_as_float((unsigned)hs << 16);
                unsigned short ls = bf16r(v - hif);
                hi[j] = (short)hs; lo[j] = (short)ls;
            }
            Ah[f][k] = hi; Al[f][k] = lo;
        }
    }
    __syncthreads();   // drains chunk-0 loads (vmcnt) + e2s

    float bestv[8], secv[8];
    int   besti[8];
    #pragma unroll
    for (int s = 0; s < 8; ++s) { bestv[s] = 3.4e38f; secv[s] = 3.4e38f; besti[s] = 0x7FFFFFFF; }

    for (int g = 0; g < 32; ++g) {
        if (g + 1 < 32) {   // async prefetch next chunk into the other buffer
            const unsigned char* src = eswz + (size_t)(g + 1) * 32768 + (size_t)tid * 16;
            unsigned char* dst = &bbuf[(g + 1) & 1][tid * 16];
            #pragma unroll
            for (int r = 0; r < 8; ++r) gl_lds16(src + r * 4096, dst + r * 4096);
        }
        const unsigned char* bb = bbuf[g & 1];

        f32x4 a00 = {0.f,0.f,0.f,0.f}, a01 = {0.f,0.f,0.f,0.f};
        f32x4 a10 = {0.f,0.f,0.f,0.f}, a11 = {0.f,0.f,0.f,0.f};
        #pragma unroll
        for (int k = 0; k < 8; ++k) {
            short8 bh0 = *(const short8*)(bb + k * 1024 + l * 16);
            short8 bl0 = *(const short8*)(bb + 8192 + k * 1024 + l * 16);
            short8 bh1 = *(const short8*)(bb + 16384 + k * 1024 + l * 16);
            short8 bl1 = *(const short8*)(bb + 16384 + 8192 + k * 1024 + l * 16);
            a00 = __builtin_amdgcn_mfma_f32_16x16x32_bf16(Ah[0][k], bh0, a00, 0, 0, 0);
            a10 = __builtin_amdgcn_mfma_f32_16x16x32_bf16(Ah[1][k], bh0, a10, 0, 0, 0);
            a01 = __builtin_amdgcn_mfma_f32_16x16x32_bf16(Ah[0][k], bh1, a01, 0, 0, 0);
            a11 = __builtin_amdgcn_mfma_f32_16x16x32_bf16(Ah[1][k], bh1, a11, 0, 0, 0);
            a00 = __builtin_amdgcn_mfma_f32_16x16x32_bf16(Al[0][k], bh0, a00, 0, 0, 0);
            a10 = __builtin_amdgcn_mfma_f32_16x16x32_bf16(Al[1][k], bh0, a10, 0, 0, 0);
            a01 = __builtin_amdgcn_mfma_f32_16x16x32_bf16(Al[0][k], bh1, a01, 0, 0, 0);
            a11 = __builtin_amdgcn_mfma_f32_16x16x32_bf16(Al[1][k], bh1, a11, 0, 0, 0);
            a00 = __builtin_amdgcn_mfma_f32_16x16x32_bf16(Ah[0][k], bl0, a00, 0, 0, 0);
            a10 = __builtin_amdgcn_mfma_f32_16x16x32_bf16(Ah[1][k], bl0, a10, 0, 0, 0);
            a01 = __builtin_amdgcn_mfma_f32_16x16x32_bf16(Ah[0][k], bl1, a01, 0, 0, 0);
            a11 = __builtin_amdgcn_mfma_f32_16x16x32_bf16(Ah[1][k], bl1, a11, 0, 0, 0);
        }

        const int col0 = g * 32 + (l & 15);
        const float e2a = e2s[col0];
        const float e2b = e2s[col0 + 16];
        #pragma unroll
        for (int f = 0; f < 2; ++f) {
            const f32x4 accA = f ? a10 : a00;
            const f32x4 accB = f ? a11 : a01;
            #pragma unroll
            for (int r = 0; r < 4; ++r) {
                const int s = f * 4 + r;
                float sA = fmaf(-2.f, accA[r], e2a);
                float sB = fmaf(-2.f, accB[r], e2b);
                bool swp = sB < sA;
                float lo = swp ? sB : sA;
                float hi = swp ? sA : sB;
                int   li = swp ? col0 + 16 : col0;
                bool upd = lo < bestv[s];
                float mx = upd ? bestv[s] : lo;      // max(bestv, lo)
                bestv[s] = upd ? lo : bestv[s];
                besti[s] = upd ? li : besti[s];
                secv[s] = fminf(secv[s], fminf(mx, hi));
            }
        }
        __syncthreads();   // drains my prefetch for g+1; protects both buffers
    }

    // merge top-2 across the 16 lanes sharing each row (xor 1,2,4,8 stays in-group)
    #pragma unroll
    for (int slot = 0; slot < 8; ++slot) {
        float bv = bestv[slot], sv = secv[slot];
        int bi = besti[slot];
        #pragma unroll
        for (int d = 1; d < 16; d <<= 1) {
            float ob = __shfl_xor(bv, d);
            int   oi = __shfl_xor(bi, d);
            float os = __shfl_xor(sv, d);
            bool take = (ob < bv) || (ob == bv && oi < bi);
            float loser = take ? bv : ob;
            bv = take ? ob : bv;
            bi = take ? oi : bi;
            sv = fminf(fminf(sv, os), loser);
        }
        if ((l & 15) == 0) {
            const int row = rb + w * 32 + (slot >> 2) * 16 + (l >> 4) * 4 + (slot & 3);
            qidx[row] = bi;
            if (sv - bv < EPS_FLAG) {
                int p = atomicAdd(flagcnt, 1);
                flaglist[p] = row;
            }
        }
    }
}

// ---------------- kernel: exact fp32 re-resolve for flagged (near-tie) rows ----------------
__global__ __launch_bounds__(256) void cleanup_kernel(
    const float* __restrict__ x, const float* __restrict__ embed,
    const float* __restrict__ e2, const int* __restrict__ flagcnt,
    const int* __restrict__ flaglist, int* __restrict__ qidx)
{
    __shared__ float xr[256];
    __shared__ float rv[256];
    __shared__ int   rix[256];
    const int tid = threadIdx.x;
    int cnt = flagcnt[0];
    if (cnt > N_TOT) cnt = N_TOT;
    for (int it = blockIdx.x; it < cnt; it += gridDim.x) {
        const int row = flaglist[it];
        const int b = row >> 12, t = row & (T_DIM - 1);
        __syncthreads();
        xr[tid] = x[(size_t)b * (D_DIM * T_DIM) + (size_t)tid * T_DIM + t];
        __syncthreads();
        float best = 3.4e38f; int bi = 0x7FFFFFFF;
        for (int q = 0; q < 4; ++q) {
            const int c = q * 256 + tid;
            const float4* ep = (const float4*)(embed + (size_t)c * D_DIM);
            float acc = 0.f;
            #pragma unroll 8
            for (int dd = 0; dd < 64; ++dd) {
                float4 ev = ep[dd];
                acc = fmaf(ev.x, xr[dd * 4 + 0], acc);
                acc = fmaf(ev.y, xr[dd * 4 + 1], acc);
                acc = fmaf(ev.z, xr[dd * 4 + 2], acc);
                acc = fmaf(ev.w, xr[dd * 4 + 3], acc);
            }
            const float s = e2[c] - 2.f * acc;
            if (s < best || (s == best && c < bi)) { best = s; bi = c; }
        }
        rv[tid] = best; rix[tid] = bi;
        __syncthreads();
        for (int off = 128; off; off >>= 1) {
            if (tid < off) {
                float ov = rv[tid + off]; int oi = rix[tid + off];
                if (ov < rv[tid] || (ov == rv[tid] && oi < rix[tid])) { rv[tid] = ov; rix[tid] = oi; }
            }
            __syncthreads();
        }
        if (tid == 0) qidx[row] = rix[0];
    }
}

// ---------------- kernel: gather z_q + loss + histogram (LDS-free) ----------------
// grid (256, 4): block = 256 t-columns x 64 d. embed float4 gathers hit L2 (1 MB);
// x reads / out writes coalesced (64 lanes = consecutive t).
__global__ __launch_bounds__(256) void gather_kernel(
    const float* __restrict__ x, const float* __restrict__ embed,
    const int* __restrict__ qidx, float* __restrict__ out,
    float* __restrict__ loss_sum, int* __restrict__ hist)
{
    const int tid = threadIdx.x;
    const int n = blockIdx.x * 256 + tid;          // global t index 0..65535
    const int b = n >> 12, t = n & (T_DIM - 1);
    const int d0 = blockIdx.y * 64;
    const int idx = qidx[n];
    if (blockIdx.y == 0) atomicAdd(&hist[idx], 1);

    const float4* ep = (const float4*)(embed + (size_t)idx * D_DIM + d0);
    const float* xp = x + (size_t)b * (D_DIM * T_DIM) + (size_t)d0 * T_DIM + t;
    float*       op = out + (size_t)b * (D_DIM * T_DIM) + (size_t)d0 * T_DIM + t;

    float local = 0.f;
    #pragma unroll 4
    for (int i = 0; i < 16; ++i) {
        const float4 ev = ep[i];
        const size_t dd = (size_t)i * 4;
        float xv0 = xp[(dd + 0) * T_DIM];
        float xv1 = xp[(dd + 1) * T_DIM];
        float xv2 = xp[(dd + 2) * T_DIM];
        float xv3 = xp[(dd + 3) * T_DIM];
        op[(dd + 0) * T_DIM] = ev.x;
        op[(dd + 1) * T_DIM] = ev.y;
        op[(dd + 2) * T_DIM] = ev.z;
        op[(dd + 3) * T_DIM] = ev.w;
        float f0 = ev.x - xv0, f1 = ev.y - xv1, f2 = ev.z - xv2, f3 = ev.w - xv3;
        local = fmaf(f0, f0, local);
        local = fmaf(f1, f1, local);
        local = fmaf(f2, f2, local);
        local = fmaf(f3, f3, local);
    }
    #pragma unroll
    for (int off = 32; off; off >>= 1) local += __shfl_down(local, off);
    __shared__ float ls[4];
    if ((tid & 63) == 0) ls[tid >> 6] = local;
    __syncthreads();
    if (tid == 0) atomicAdd(loss_sum, ls[0] + ls[1] + ls[2] + ls[3]);
}

// ---------------- kernel: entropy / finalize ----------------
__global__ __launch_bounds__(256) void finalize_kernel(
    const int* __restrict__ hist, const float* __restrict__ loss_sum,
    float* __restrict__ out)
{
    const int tid = threadIdx.x;
    float acc = 0.f;
    #pragma unroll
    for (int i = tid; i < K_NUM; i += 256) {
        const float p = (float)hist[i] * (1.f / (float)N_TOT);
        acc += p * logf(p + 1e-10f);
    }
    #pragma unroll
    for (int off = 32; off; off >>= 1) acc += __shfl_down(acc, off);
    __shared__ float ls[4];
    if ((tid & 63) == 0) ls[tid >> 6] = acc;
    __syncthreads();
    if (tid == 0) {
        const float H = -(ls[0] + ls[1] + ls[2] + ls[3]);
        const size_t base = (size_t)N_TOT * D_DIM;   // 16777216
        out[base] = 1.25f * loss_sum[0] * (1.f / 16777216.f);
        const float kld = (float)(6.931471805599453 * 4096.0);  // log(1024)*T
        #pragma unroll
        for (int i = 0; i < 16; ++i) out[base + 1 + i] = kld;
        out[base + 17] = expf(H);
    }
}

extern "C" void kernel_launch(void* const* d_in, const int* in_sizes, int n_in,
                              void* d_out, int out_size, void* d_ws, size_t ws_size,
                              hipStream_t stream)
{
    const float* x     = (const float*)d_in[0];   // (16, 256, 4096) f32
    const float* embed = (const float*)d_in[1];   // (1024, 256) f32
    float* out = (float*)d_out;

    char* ws = (char*)d_ws;
    int*   flagcnt  = (int*)(ws + WS_FLAGCNT);
    float* loss_sum = (float*)(ws + WS_LOSS);
    int*   hist     = (int*)(ws + WS_HIST);
    float* e2       = (float*)(ws + WS_E2);
    int*   qidx     = (int*)(ws + WS_QIDX);
    int*   flaglist = (int*)(ws + WS_FLAGLIST);
    unsigned char* eswz = (unsigned char*)(ws + WS_ESWZ);

    hipMemsetAsync(ws, 0, 4160, stream);  // flagcnt + loss_sum + hist

    e2_kernel<<<K_NUM / 4, 256, 0, stream>>>(embed, e2);
    prep_eswz_kernel<<<128, 256, 0, stream>>>(embed, eswz);
    argmin_mfma_kernel<<<N_TOT / 128, 256, 0, stream>>>(x, eswz, e2, qidx, flagcnt, flaglist);
    cleanup_kernel<<<256, 256, 0, stream>>>(x, embed, e2, flagcnt, flaglist, qidx);
    gather_kernel<<<dim3(N_TOT / 256, 4), 256, 0, stream>>>(x, embed, qidx, out, loss_sum, hist);
    finalize_kernel<<<1, 256, 0, stream>>>(hist, loss_sum, out);
}